// Round 10
// baseline (46.925 us; speedup 1.0000x reference)
//
#include <hip/hip_runtime.h>

// Top1Gate via bf16x3-split MFMA GEMM, v10.
// logits = x @ W^T [16384,64]; idx = argmax; scores = max; mask = one-hot.
// Output flat (float32): [idx 16384][scores 16384][mask 16384*64]
//
// v10 vs v6: DRAM run length 512B -> 2KB. BM=16, chunk = 16 rows x 512 k
// (32 KB), 4 chunks, 2-slot ring (70 KB LDS, 2 blocks/CU). B pre-split in wf
// (R7: raw-W loads uncoalesce), 4 static-indexed register BSets, halves
// reloaded after last read (kb1/kb3). Per-kb waits are vmcnt-only (B is
// wave-private); 9 barriers/block vs v6's 33. Read swizzle col^(r&7) spreads
// the 16-row column read over all 8 bank quads (v6 hit only 4).

typedef float  f32x4  __attribute__((ext_vector_type(4)));
typedef short  bf16x8 __attribute__((ext_vector_type(8)));

constexpr int BATCH = 16384;
constexpr int DM    = 2048;
constexpr int NE    = 64;
constexpr int BM    = 16;          // rows per block
constexpr int NT    = 256;         // 4 waves = 4 k-quarters

// wf layout (d_ws, ushort): [ks=64][term=2][tile=4][lane=64][j=8]
// value = w_term[expert = tile*16 + (lane&15)][k = ks*32 + (lane>>4)*8 + j]

__device__ __forceinline__ void split_bf16(float f, unsigned short& hi, unsigned short& lo) {
    unsigned u  = __float_as_uint(f);
    unsigned h  = (u + 0x8000u) >> 16;           // round-half-up to bf16
    float    hf = __uint_as_float(h << 16);
    unsigned l  = __float_as_uint(f - hf) >> 16; // truncate residual
    hi = (unsigned short)h;
    lo = (unsigned short)l;
}

__global__ __launch_bounds__(256, 1)
void wconv_kernel(const float* __restrict__ w, unsigned short* __restrict__ wf) {
    int i  = blockIdx.x * 256 + threadIdx.x;     // 0..131071
    int ks = i >> 11;
    int n  = (i >> 9) & 3;
    int l  = (i >> 3) & 63;
    int j  = i & 7;
    int e  = n * 16 + (l & 15);
    int k  = ks * 32 + (l >> 4) * 8 + j;
    float v = w[(size_t)e * DM + k];
    unsigned short hi, lo;
    split_bf16(v, hi, lo);
    int base = ((ks * 2 + 0) * 4 + n) * 512 + l * 8 + j;
    wf[base]        = hi;               // term 0
    wf[base + 2048] = lo;               // term 1
}

struct BSet { bf16x8 v[8]; };   // [term=2(hi,lo)][tile=4] for one 32-k step

#define WAITV(N) do { asm volatile("s_waitcnt vmcnt(" #N ")" ::: "memory"); \
                      __builtin_amdgcn_sched_barrier(0); } while (0)
#define BARR     do { __builtin_amdgcn_sched_barrier(0); \
                      __builtin_amdgcn_s_barrier(); \
                      __builtin_amdgcn_sched_barrier(0); } while (0)

__global__ __launch_bounds__(NT, 2)
void gate_kernel(const float* __restrict__ x,
                 const unsigned short* __restrict__ wf,
                 float* __restrict__ out) {
    __shared__ alignas(16) float xs[2][BM * 128 * 4];  // 2 slots x 32 KB
    __shared__ float lg[BM][NE + 1];                   // stride 65
    __shared__ int   s_idx[BM];

    const int t     = threadIdx.x;
    const int lane  = t & 63;
    const int q     = t >> 6;               // k-quarter within kblk
    const int row0  = blockIdx.x * BM;
    const int phase = blockIdx.x & 3;       // de-phase over the 4 k-slabs

    f32x4 acc[4];
    #pragma unroll
    for (int n = 0; n < 4; ++n) acc[n] = (f32x4){0.f, 0.f, 0.f, 0.f};

    auto kposA = [&](int c) { return (c + phase) & 3; };   // actual 512-k slab

    // stage chunk c (16 rows x 512 k = 2048 f4) into slot c&1; 8 loads/thread.
    // Per-row global run = 2 KB (16B units permuted within 512B by the swizzle).
    auto stage_x = [&](int c) {
        const float* xg = x + (size_t)row0 * DM + kposA(c) * 512;
        float* dst = &xs[c & 1][0];
        #pragma unroll
        for (int i = 0; i < 8; ++i) {
            int d    = i * NT + t;          // 0..2047 linear dest f4 slot
            int r    = d >> 7;              // row 0..15
            int col  = d & 127;
            int scol = col ^ (r & 7);       // pre-swizzled source (linear LDS dest)
            __builtin_amdgcn_global_load_lds(
                (const __attribute__((address_space(1))) void*)(xg + (size_t)r * DM + scol * 4),
                (__attribute__((address_space(3))) void*)(dst + d * 4),
                16, 0, 0);
        }
    };

    // load this wave's B fragments for chunk c, kblk kb (k-step = quarter q):
    // 8 KB/wave contiguous from wf (L2-hot), 8 loads.
    auto load_b = [&](int c, int kb, BSet& B) {
        int ks = (kposA(c) * 4 + kb) * 4 + q;
        const unsigned short* wg = wf + (size_t)ks * 4096 + lane * 8;
        #pragma unroll
        for (int f = 0; f < 8; ++f)         // f = term*4 + tile
            B.v[f] = *(const bf16x8*)(wg + (size_t)f * 512);
    };

    // compute kblk kb of chunk c: 2 swizzled ds_read_b128 + split + 12 MFMA
    auto compute = [&](int c, int kb, const BSet& B) {
        const float* src = &xs[c & 1][0];
        const int rA = lane & 15;
        const int c0 = kb * 32 + q * 8 + ((lane >> 4) << 1);
        f32x4 a0 = *(const f32x4*)(src + (rA * 128 + ((c0 + 0) ^ (rA & 7))) * 4);
        f32x4 a1 = *(const f32x4*)(src + (rA * 128 + ((c0 + 1) ^ (rA & 7))) * 4);
        bf16x8 ahi, alo;
        #pragma unroll
        for (int j = 0; j < 8; ++j) {
            float f = (j < 4) ? a0[j] : a1[j - 4];
            unsigned short h, l;
            split_bf16(f, h, l);
            ahi[j] = (short)h;
            alo[j] = (short)l;
        }
        #pragma unroll
        for (int n = 0; n < 4; ++n) {
            acc[n] = __builtin_amdgcn_mfma_f32_16x16x32_bf16(ahi, B.v[0 + n], acc[n], 0, 0, 0);
            acc[n] = __builtin_amdgcn_mfma_f32_16x16x32_bf16(ahi, B.v[4 + n], acc[n], 0, 0, 0);
            acc[n] = __builtin_amdgcn_mfma_f32_16x16x32_bf16(alo, B.v[0 + n], acc[n], 0, 0, 0);
        }
    };

    BSet B0_, B1_, B2_, B3_;   // static kb-indexed rotating buffers

    // ---- prologue: B(0)x4:32, X0:8, X1:8 = 48 outstanding
    load_b(0, 0, B0_); load_b(0, 1, B1_); load_b(0, 2, B2_); load_b(0, 3, B3_);
    stage_x(0);
    stage_x(1);
    WAITV(8);           // drain B(0) + X0; leave X1
    BARR;

    // ---- chunk 0 (all B(0)/X0 drained; reload halves after last reader)
    compute(0, 0, B0_);
    compute(0, 1, B1_);
    load_b(1, 0, B0_); load_b(1, 1, B1_);        // +16 -> [X1:8, B1a:16]
    compute(0, 2, B2_);
    compute(0, 3, B3_);
    load_b(1, 2, B2_); load_b(1, 3, B3_);        // +16 -> [X1, B1a, B1b] = 40

    // ---- chunk 1
    BARR;                                        // slot 0 free
    stage_x(2);                                  // -> 48
    WAITV(32);          // drain X1 + B(1,0)
    BARR;               // X1 visible to all waves
    compute(1, 0, B0_);
    WAITV(24);          // drain B(1,1)
    compute(1, 1, B1_);
    load_b(2, 0, B0_); load_b(2, 1, B1_);        // -> 40
    WAITV(32);          // drain B(1,2)
    compute(1, 2, B2_);
    WAITV(24);          // drain B(1,3)
    compute(1, 3, B3_);
    load_b(2, 2, B2_); load_b(2, 3, B3_);        // -> [X2:8, B2a:16, B2b:16] = 40

    // ---- chunk 2
    BARR;                                        // slot 1 free
    stage_x(3);                                  // -> 48
    WAITV(32);          // drain X2 + B(2,0)
    BARR;
    compute(2, 0, B0_);
    WAITV(24);          // drain B(2,1)
    compute(2, 1, B1_);
    load_b(3, 0, B0_); load_b(3, 1, B1_);        // -> 40
    WAITV(32);          // drain B(2,2)
    compute(2, 2, B2_);
    WAITV(24);          // drain B(2,3)
    compute(2, 3, B3_);
    load_b(3, 2, B2_); load_b(3, 3, B3_);        // -> [X3:8, B3a:16, B3b:16] = 40

    // ---- chunk 3 (no further issues)
    BARR;
    WAITV(24);          // drain X3 + B(3,0)
    BARR;
    compute(3, 0, B0_);
    WAITV(16);          // drain B(3,1)
    compute(3, 1, B1_);
    WAITV(8);           // drain B(3,2)
    compute(3, 2, B2_);
    WAITV(0);
    compute(3, 3, B3_);
    __syncthreads();

    // ---- 4-way k-quarter reduce into lg (deterministic serial order)
    // C/D layout: row_local = (lane>>4)*4 + j, col = n*16 + (lane&15)
    const int rb = (lane >> 4) << 2;
    const int cb = lane & 15;
    if (q == 0) {
        #pragma unroll
        for (int n = 0; n < 4; ++n)
            #pragma unroll
            for (int j = 0; j < 4; ++j)
                lg[rb + j][n * 16 + cb] = acc[n][j];
    }
    __syncthreads();
    if (q == 1) {
        #pragma unroll
        for (int n = 0; n < 4; ++n)
            #pragma unroll
            for (int j = 0; j < 4; ++j)
                lg[rb + j][n * 16 + cb] += acc[n][j];
    }
    __syncthreads();
    if (q == 2) {
        #pragma unroll
        for (int n = 0; n < 4; ++n)
            #pragma unroll
            for (int j = 0; j < 4; ++j)
                lg[rb + j][n * 16 + cb] += acc[n][j];
    }
    __syncthreads();
    if (q == 3) {
        #pragma unroll
        for (int n = 0; n < 4; ++n)
            #pragma unroll
            for (int j = 0; j < 4; ++j)
                lg[rb + j][n * 16 + cb] += acc[n][j];
    }
    __syncthreads();

    if (t < BM) {
        float m  = lg[t][0];
        int   mi = 0;
        #pragma unroll
        for (int e = 1; e < NE; ++e) {
            float v = lg[t][e];
            if (v > m) { m = v; mi = e; }
        }
        s_idx[t] = mi;
        out[row0 + t]         = (float)mi;
        out[BATCH + row0 + t] = m;
    }
    __syncthreads();

    // one-hot mask: 16 rows x 64 = 1024 floats; 1 f32x4/thread, coalesced
    float* mask = out + 2 * (size_t)BATCH;
    int r  = t >> 4;
    int c0 = (t & 15) * 4;
    int mi = s_idx[r];
    f32x4 v;
    #pragma unroll
    for (int j = 0; j < 4; ++j) v[j] = (c0 + j == mi) ? 1.0f : 0.0f;
    *(f32x4*)&mask[(size_t)(row0 + r) * NE + c0] = v;
}

extern "C" void kernel_launch(void* const* d_in, const int* in_sizes, int n_in,
                              void* d_out, int out_size, void* d_ws, size_t ws_size,
                              hipStream_t stream) {
    const float* x = (const float*)d_in[0];
    const float* w = (const float*)d_in[1];
    float* out     = (float*)d_out;
    unsigned short* wf = (unsigned short*)d_ws;   // 512 KB

    wconv_kernel<<<dim3(512), dim3(256), 0, stream>>>(w, wf);
    gate_kernel<<<dim3(BATCH / BM), dim3(NT), 0, stream>>>(x, wf, out);
}

// Round 11
// 43.654 us; speedup vs baseline: 1.0749x; 1.0749x over previous
//
#include <hip/hip_runtime.h>

// Top1Gate via bf16x3-split MFMA GEMM, v11  (= v6 structure + 1KB DRAM runs).
// logits = x @ W^T [16384,64]; idx = argmax; scores = max; mask = one-hot.
// Output flat (float32): [idx 16384][scores 16384][mask 16384*64]
//
// v11 vs v6: chunk 16r x 256k (16 KB) -> every global_load_lds covers one
// FULL 1KB contiguous row-run (DRAM row-buffer utilization ~2x of 512B).
// Kept: 8-way slab de-phase (R5), B shared across h-pair (R6), B 2 chunks
// ahead, 4-slot ring (64KB, 2 blocks/CU), wconv pre-pass (R7 lesson).
// Fixed: read swizzle col^(r&7) (1-granular; v6's (r&7)<<2 left 8-way LDS
// conflicts). Uniform vmcnt(24) steady state, hand-traced; tail 4/0.

typedef float  f32x4  __attribute__((ext_vector_type(4)));
typedef short  bf16x8 __attribute__((ext_vector_type(8)));

constexpr int BATCH = 16384;
constexpr int DM    = 2048;
constexpr int NE    = 64;
constexpr int BM    = 32;          // rows per block
constexpr int NT    = 256;         // 4 waves = 4 k-quarters (64k each)
// chunk = 16 rows x 256k = 16 KB; 16 chunks: c -> (h = c&1, slab = c>>1 of 8)

// wf layout (d_ws, ushort): [ks=64][term=2][tile=4][lane=64][j=8]
// value = w_term[expert = tile*16 + (lane&15)][k = ks*32 + (lane>>4)*8 + j]

__device__ __forceinline__ void split_bf16(float f, unsigned short& hi, unsigned short& lo) {
    unsigned u  = __float_as_uint(f);
    unsigned h  = (u + 0x8000u) >> 16;           // round-half-up to bf16
    float    hf = __uint_as_float(h << 16);
    unsigned l  = __float_as_uint(f - hf) >> 16; // truncate residual
    hi = (unsigned short)h;
    lo = (unsigned short)l;
}

__global__ __launch_bounds__(256, 1)
void wconv_kernel(const float* __restrict__ w, unsigned short* __restrict__ wf) {
    int i  = blockIdx.x * 256 + threadIdx.x;     // 0..131071
    int ks = i >> 11;
    int n  = (i >> 9) & 3;
    int l  = (i >> 3) & 63;
    int j  = i & 7;
    int e  = n * 16 + (l & 15);
    int k  = ks * 32 + (l >> 4) * 8 + j;
    float v = w[(size_t)e * DM + k];
    unsigned short hi, lo;
    split_bf16(v, hi, lo);
    int base = ((ks * 2 + 0) * 4 + n) * 512 + l * 8 + j;
    wf[base]        = hi;               // term 0
    wf[base + 2048] = lo;               // term 1
}

struct BSet  { bf16x8 v[8]; };   // [term=2(hi,lo)][tile=4] for one 32-k step
struct BPair { BSet a, b; };     // the 2 k-steps of this wave's 64k quarter

#define WAITV(N) do { asm volatile("s_waitcnt vmcnt(" #N ")" ::: "memory"); \
                      __builtin_amdgcn_sched_barrier(0); } while (0)
#define BARR     do { __builtin_amdgcn_sched_barrier(0); \
                      __builtin_amdgcn_s_barrier(); \
                      __builtin_amdgcn_sched_barrier(0); } while (0)

__global__ __launch_bounds__(NT, 2)
void gate_kernel(const float* __restrict__ x,
                 const unsigned short* __restrict__ wf,
                 float* __restrict__ out) {
    __shared__ alignas(16) float xs[4][16 * 64 * 4];   // 4-slot ring x 16 KB
    __shared__ float lg[BM][NE + 1];                   // stride 65
    __shared__ int   s_idx[BM];

    const int t     = threadIdx.x;
    const int lane  = t & 63;
    const int q     = t >> 6;                // k-quarter 0..3 (64k each)
    const int row0  = blockIdx.x * BM;
    const int phase = blockIdx.x & 7;        // 8-way slab de-phase

    f32x4 acc[2][4];
    #pragma unroll
    for (int h = 0; h < 2; ++h)
        #pragma unroll
        for (int n = 0; n < 4; ++n) acc[h][n] = (f32x4){0.f, 0.f, 0.f, 0.f};

    auto sph = [&](int ss) { return (ss + phase) & 7; };   // physical 256k slab

    // stage chunk c: 16 rows x 256k = 1024 f4; 4 instrs/thread, each covering
    // ONE full 1KB contiguous row (16B units permuted in-row by the swizzle).
    auto stage_x = [&](int c) {
        const int h = c & 1;
        const float* xg = x + (size_t)(row0 + h * 16) * DM + sph(c >> 1) * 256;
        float* dst = &xs[c & 3][0];
        #pragma unroll
        for (int i = 0; i < 4; ++i) {
            int d  = i * NT + t;            // 0..1023 linear dest f4 slot
            int r  = d >> 6;                // row 0..15 (one row per instr)
            int sd = d & 63;
            int sr = sd ^ (r & 7);          // pre-swizzled source, linear dest
            __builtin_amdgcn_global_load_lds(
                (const __attribute__((address_space(1))) void*)(xg + (size_t)r * DM + sr * 4),
                (__attribute__((address_space(3))) void*)(dst + d * 4),
                16, 0, 0);
        }
    };

    // load one 32-k BSet (8 x 1KB contiguous, L2-hot)
    auto load_bs = [&](int ks, BSet& B) {
        const unsigned short* wg = wf + (size_t)ks * 4096 + lane * 8;
        #pragma unroll
        for (int f = 0; f < 8; ++f)         // f = term*4 + tile
            B.v[f] = *(const bf16x8*)(wg + (size_t)f * 512);
    };
    // this wave's B pair for slab ss: ks = slab*8 + q*2 + {0,1}  (16 loads)
    auto load_pair = [&](int ss, BPair& P) {
        int base = sph(ss) * 8 + q * 2;
        load_bs(base + 0, P.a);
        load_bs(base + 1, P.b);
    };

    // compute chunk c (row-half hh literal): 2 k-steps, 4 ds_read + 24 MFMA
    auto compute = [&](int c, int hh, const BPair& P) {
        const float* src = &xs[c & 3][0];
        const int rA = lane & 15;
        const int xr = rA & 7;
        #pragma unroll
        for (int kk = 0; kk < 2; ++kk) {
            const BSet& B = kk ? P.b : P.a;
            const int c0 = q * 16 + kk * 8 + ((lane >> 4) << 1);
            f32x4 a0 = *(const f32x4*)(src + (rA * 64 + ((c0 + 0) ^ xr)) * 4);
            f32x4 a1 = *(const f32x4*)(src + (rA * 64 + ((c0 + 1) ^ xr)) * 4);
            bf16x8 ahi, alo;
            #pragma unroll
            for (int j = 0; j < 8; ++j) {
                float f = (j < 4) ? a0[j] : a1[j - 4];
                unsigned short h, l;
                split_bf16(f, h, l);
                ahi[j] = (short)h;
                alo[j] = (short)l;
            }
            #pragma unroll
            for (int n = 0; n < 4; ++n) {
                acc[hh][n] = __builtin_amdgcn_mfma_f32_16x16x32_bf16(ahi, B.v[0 + n], acc[hh][n], 0, 0, 0);
                acc[hh][n] = __builtin_amdgcn_mfma_f32_16x16x32_bf16(ahi, B.v[4 + n], acc[hh][n], 0, 0, 0);
                acc[hh][n] = __builtin_amdgcn_mfma_f32_16x16x32_bf16(alo, B.v[0 + n], acc[hh][n], 0, 0, 0);
            }
        }
    };

    BPair PA, PB;

    // prologue: B(slab0):16, X0:4, X1:4 = 24 outstanding
    load_pair(0, PA);
    stage_x(0);
    stage_x(1);

    // steady state (hand-traced): every chunk issues then waits vmcnt(24);
    // drains exactly {B for this chunk (2-chunk-old), X(c)}; leaves 2 x-chunks
    // (32 KB) + next B pair in flight. Slab pairs: PA = even slab-step.
    #pragma unroll 1
    for (int ss = 0; ss < 6; ss += 2) {
        const int c = 2 * ss;
        load_pair(ss + 1, PB);
        stage_x(c + 2);
        WAITV(24); BARR;
        compute(c + 0, 0, PA);
        stage_x(c + 3);
        WAITV(24); BARR;
        compute(c + 1, 1, PA);
        load_pair(ss + 2, PA);
        stage_x(c + 4);
        WAITV(24); BARR;
        compute(c + 2, 0, PB);
        stage_x(c + 5);
        WAITV(24); BARR;
        compute(c + 3, 1, PB);
    }
    // ss=6: chunks 12,13 (PA = slab 6)
    load_pair(7, PB);
    stage_x(14);
    WAITV(24); BARR;
    compute(12, 0, PA);
    stage_x(15);
    WAITV(24); BARR;
    compute(13, 1, PA);
    // ss=7: chunks 14,15 (PB = slab 7); queue = [B7:16, X14:4, X15:4]
    WAITV(4);  BARR;            // drain B7 + X14, leave X15
    compute(14, 0, PB);
    WAITV(0);  BARR;            // drain X15
    compute(15, 1, PB);
    __syncthreads();

    // 4-way k-quarter reduce into lg (deterministic serial order)
    // C/D layout: row_local = (lane>>4)*4 + j, col = n*16 + (lane&15)
    const int rb = (lane >> 4) << 2;
    const int cb = lane & 15;
    if (q == 0) {
        #pragma unroll
        for (int h = 0; h < 2; ++h)
            #pragma unroll
            for (int n = 0; n < 4; ++n)
                #pragma unroll
                for (int j = 0; j < 4; ++j)
                    lg[h * 16 + rb + j][n * 16 + cb] = acc[h][n][j];
    }
    __syncthreads();
    if (q == 1) {
        #pragma unroll
        for (int h = 0; h < 2; ++h)
            #pragma unroll
            for (int n = 0; n < 4; ++n)
                #pragma unroll
                for (int j = 0; j < 4; ++j)
                    lg[h * 16 + rb + j][n * 16 + cb] += acc[h][n][j];
    }
    __syncthreads();
    if (q == 2) {
        #pragma unroll
        for (int h = 0; h < 2; ++h)
            #pragma unroll
            for (int n = 0; n < 4; ++n)
                #pragma unroll
                for (int j = 0; j < 4; ++j)
                    lg[h * 16 + rb + j][n * 16 + cb] += acc[h][n][j];
    }
    __syncthreads();
    if (q == 3) {
        #pragma unroll
        for (int h = 0; h < 2; ++h)
            #pragma unroll
            for (int n = 0; n < 4; ++n)
                #pragma unroll
                for (int j = 0; j < 4; ++j)
                    lg[h * 16 + rb + j][n * 16 + cb] += acc[h][n][j];
    }
    __syncthreads();

    if (t < BM) {
        float m  = lg[t][0];
        int   mi = 0;
        #pragma unroll
        for (int e = 1; e < NE; ++e) {
            float v = lg[t][e];
            if (v > m) { m = v; mi = e; }
        }
        s_idx[t] = mi;
        out[row0 + t]         = (float)mi;
        out[BATCH + row0 + t] = m;
    }
    __syncthreads();

    // one-hot mask: 32 rows x 64 = 2048 floats; 8/thread, coalesced f32x4
    float* mask = out + 2 * (size_t)BATCH;
    int r  = t >> 3;
    int c0 = (t & 7) * 8;
    int mi = s_idx[r];
    #pragma unroll
    for (int i = 0; i < 2; ++i) {
        f32x4 v;
        #pragma unroll
        for (int j = 0; j < 4; ++j) v[j] = (c0 + i * 4 + j == mi) ? 1.0f : 0.0f;
        *(f32x4*)&mask[(size_t)(row0 + r) * NE + c0 + i * 4] = v;
    }
}

extern "C" void kernel_launch(void* const* d_in, const int* in_sizes, int n_in,
                              void* d_out, int out_size, void* d_ws, size_t ws_size,
                              hipStream_t stream) {
    const float* x = (const float*)d_in[0];
    const float* w = (const float*)d_in[1];
    float* out     = (float*)d_out;
    unsigned short* wf = (unsigned short*)d_ws;   // 512 KB

    wconv_kernel<<<dim3(512), dim3(256), 0, stream>>>(w, wf);
    gate_kernel<<<dim3(BATCH / BM), dim3(NT), 0, stream>>>(x, wf, out);
}

// Round 12
// 38.559 us; speedup vs baseline: 1.2170x; 1.1321x over previous
//
#include <hip/hip_runtime.h>

// Top1Gate via bf16x3-split MFMA GEMM, v13  (= v6 with W staged in-kernel).
// logits = x @ W^T [16384,64]; idx = argmax; scores = max; mask = one-hot.
// Output flat (float32): [idx 16384][scores 16384][mask 16384*64]
//
// v13 vs v6: wconv pre-pass ELIMINATED the right way (R7 failed with raw
// fragment loads, 16-way uncoalesced). W slab (64e x 128k fp32 = 32 KB/kblk)
// is staged COALESCED into LDS via global_load_lds (512B row-runs, same
// pattern as x), fragments read back with XOR-swizzled ds_read_b128, hi/lo
// split in VALU once per pair, reused across both h-chunks (R6 pairing).
// Single-buffer ws: one L2-latency wait per pair, paid once, half-hidden by
// the co-resident block. X path identical to v6: 4-slot ring, 2 chunks in
// flight post-wait, 16-way de-phase. LDS 72.6 KB -> 2 blocks/CU.

typedef float  f32x4  __attribute__((ext_vector_type(4)));
typedef short  bf16x8 __attribute__((ext_vector_type(8)));

constexpr int BATCH = 16384;
constexpr int DM    = 2048;
constexpr int NE    = 64;
constexpr int BM    = 32;          // rows per block
constexpr int NT    = 256;         // 4 waves = 4 k-quarters
// chunk = 16 rows x 128 k = 8 KB; 32 chunks; pair p = {2p (h0), 2p+1 (h1)},
// both sharing kblk kb(p). 16 pairs.

__device__ __forceinline__ void split_bf16(float f, unsigned short& hi, unsigned short& lo) {
    unsigned u  = __float_as_uint(f);
    unsigned h  = (u + 0x8000u) >> 16;           // round-half-up to bf16
    float    hf = __uint_as_float(h << 16);
    unsigned l  = __float_as_uint(f - hf) >> 16; // truncate residual
    hi = (unsigned short)h;
    lo = (unsigned short)l;
}

struct BSet { bf16x8 v[8]; };   // [term=2(hi,lo)][tile=4] for this wave's 32-k step

#define WAITV(N) do { asm volatile("s_waitcnt vmcnt(" #N ")" ::: "memory"); \
                      __builtin_amdgcn_sched_barrier(0); } while (0)
#define BARR     do { __builtin_amdgcn_sched_barrier(0); \
                      __builtin_amdgcn_s_barrier(); \
                      __builtin_amdgcn_sched_barrier(0); } while (0)

__global__ __launch_bounds__(NT, 2)
void gate_kernel(const float* __restrict__ x,
                 const float* __restrict__ w,
                 float* __restrict__ out) {
    __shared__ alignas(16) float xs[4][16 * 32 * 4];   // 4-slot ring x 8 KB = 32 KB
    __shared__ alignas(16) float ws4[64 * 32 * 4];     // W slab: 64 e x 32 f4 = 32 KB
    __shared__ float lg[BM][NE + 1];                   // stride 65
    __shared__ int   s_idx[BM];

    const int t     = threadIdx.x;
    const int lane  = t & 63;
    const int q     = t >> 6;                // k-quarter 0..3 (32k each)
    const int row0  = blockIdx.x * BM;
    const int phase = blockIdx.x & 15;       // 16-way kblk de-phase (R5)

    f32x4 acc[2][4];
    #pragma unroll
    for (int h = 0; h < 2; ++h)
        #pragma unroll
        for (int n = 0; n < 4; ++n) acc[h][n] = (f32x4){0.f, 0.f, 0.f, 0.f};

    auto kb = [&](int p) { return (p + phase) & 15; };

    // stage x chunk c (16 rows x 128 k = 512 f4) into ring slot c&3; 2/thread.
    // 512B row-runs; source pre-swizzled (1-granular XOR), LDS dest linear.
    auto stage_x = [&](int c) {
        const int h = c & 1;
        const float* xg = x + (size_t)(row0 + h * 16) * DM + kb(c >> 1) * 128;
        float* dst = &xs[c & 3][0];
        #pragma unroll
        for (int i = 0; i < 2; ++i) {
            int d  = i * NT + t;            // 0..511 linear dest f4 slot
            int r  = d >> 5;                // row 0..15 (32 slots each)
            int sd = d & 31;
            int sr = sd ^ (r & 7);          // pre-swizzled source
            __builtin_amdgcn_global_load_lds(
                (const __attribute__((address_space(1))) void*)(xg + (size_t)r * DM + sr * 4),
                (__attribute__((address_space(3))) void*)(dst + d * 4),
                16, 0, 0);
        }
    };

    // stage W slab for pair p: 64 experts x 128 k fp32 = 2048 f4; 8/thread.
    // Coalesced 512B row-runs (same pattern as x); source pre-swizzled.
    auto stage_w = [&](int p) {
        const float* wg = w + (size_t)kb(p) * 128;
        #pragma unroll
        for (int i = 0; i < 8; ++i) {
            int d  = i * NT + t;            // 0..2047 linear dest f4 slot
            int e  = d >> 5;                // expert 0..63 (32 slots each)
            int sd = d & 31;
            int sr = sd ^ (e & 7);          // pre-swizzled source
            __builtin_amdgcn_global_load_lds(
                (const __attribute__((address_space(1))) void*)(wg + (size_t)e * DM + sr * 4),
                (__attribute__((address_space(3))) void*)(ws4 + d * 4),
                16, 0, 0);
        }
    };

    // compute chunk c (row-half hh literal) with this wave's pre-split BSet
    auto compute = [&](int c, int hh, const BSet& B) {
        const float* src = &xs[c & 3][0];
        const int rA = lane & 15;
        const int s0 = q * 8 + ((lane >> 4) << 1);
        f32x4 a0 = *(const f32x4*)(src + (size_t)(rA * 32 + ((s0 + 0) ^ (rA & 7))) * 4);
        f32x4 a1 = *(const f32x4*)(src + (size_t)(rA * 32 + ((s0 + 1) ^ (rA & 7))) * 4);
        bf16x8 ahi, alo;
        #pragma unroll
        for (int j = 0; j < 8; ++j) {
            float f = (j < 4) ? a0[j] : a1[j - 4];
            unsigned short h, l;
            split_bf16(f, h, l);
            ahi[j] = (short)h;
            alo[j] = (short)l;
        }
        #pragma unroll
        for (int n = 0; n < 4; ++n) {
            acc[hh][n] = __builtin_amdgcn_mfma_f32_16x16x32_bf16(ahi, B.v[0 + n], acc[hh][n], 0, 0, 0);
            acc[hh][n] = __builtin_amdgcn_mfma_f32_16x16x32_bf16(ahi, B.v[4 + n], acc[hh][n], 0, 0, 0);
            acc[hh][n] = __builtin_amdgcn_mfma_f32_16x16x32_bf16(alo, B.v[0 + n], acc[hh][n], 0, 0, 0);
        }
    };

    // per pair: read this wave's W fragments from ws4 (8 swizzled ds_read_b128),
    // split once (bit-identical to old wconv), compute both h-chunks.
    auto pairbody = [&](int p) {
        BSet S;
        #pragma unroll
        for (int n = 0; n < 4; ++n) {
            const int e  = n * 16 + (lane & 15);
            const int s0 = q * 8 + ((lane >> 4) << 1);
            f32x4 w0 = *(const f32x4*)&ws4[(size_t)(e * 32 + ((s0 + 0) ^ (e & 7))) * 4];
            f32x4 w1 = *(const f32x4*)&ws4[(size_t)(e * 32 + ((s0 + 1) ^ (e & 7))) * 4];
            bf16x8 hi8, lo8;
            #pragma unroll
            for (int j = 0; j < 8; ++j) {
                float f = (j < 4) ? w0[j] : w1[j - 4];
                unsigned short h, l;
                split_bf16(f, h, l);
                hi8[j] = (short)h;
                lo8[j] = (short)l;
            }
            S.v[n]     = hi8;
            S.v[4 + n] = lo8;
        }
        compute(2 * p + 0, 0, S);
        compute(2 * p + 1, 1, S);
    };

    // prologue: queue = [X0:2, X1:2, W0:8, X2:2, X3:2] = 16
    stage_x(0);
    stage_x(1);
    stage_w(0);
    stage_x(2);
    stage_x(3);
    WAITV(4);            // drain X0, X1, W0; leave X2, X3 (2 chunks in flight)
    BARR;
    pairbody(0);

    // steady pairs 1..14: boundary barrier protects ws4 + reused xs slots;
    // issue [W(p):8, X(2p+2):2, X(2p+3):2]; queue = [X(2p):2, X(2p+1):2,
    // W(p):8, X(2p+2):2, X(2p+3):2] = 16 -> WAITV(4) drains thru W(p),
    // leaves 2 x-chunks (consumed next pair: ~2 chunk-periods of slack).
    #pragma unroll 1
    for (int p = 1; p < 15; ++p) {
        BARR;
        stage_w(p);
        stage_x(2 * p + 2);
        stage_x(2 * p + 3);
        WAITV(4);
        BARR;
        pairbody(p);
    }

    // tail pair 15: queue = [X30:2, X31:2, W15:8] -> drain all
    BARR;
    stage_w(15);
    WAITV(0);
    BARR;
    pairbody(15);
    __syncthreads();

    // 4-way k-quarter reduce into lg (deterministic serial order)
    // C/D layout: row_local = (lane>>4)*4 + j, col = n*16 + (lane&15)
    const int rb = (lane >> 4) << 2;
    const int cb = lane & 15;
    if (q == 0) {
        #pragma unroll
        for (int h = 0; h < 2; ++h)
            #pragma unroll
            for (int n = 0; n < 4; ++n)
                #pragma unroll
                for (int j = 0; j < 4; ++j)
                    lg[h * 16 + rb + j][n * 16 + cb] = acc[h][n][j];
    }
    __syncthreads();
    if (q == 1) {
        #pragma unroll
        for (int h = 0; h < 2; ++h)
            #pragma unroll
            for (int n = 0; n < 4; ++n)
                #pragma unroll
                for (int j = 0; j < 4; ++j)
                    lg[h * 16 + rb + j][n * 16 + cb] += acc[h][n][j];
    }
    __syncthreads();
    if (q == 2) {
        #pragma unroll
        for (int h = 0; h < 2; ++h)
            #pragma unroll
            for (int n = 0; n < 4; ++n)
                #pragma unroll
                for (int j = 0; j < 4; ++j)
                    lg[h * 16 + rb + j][n * 16 + cb] += acc[h][n][j];
    }
    __syncthreads();
    if (q == 3) {
        #pragma unroll
        for (int h = 0; h < 2; ++h)
            #pragma unroll
            for (int n = 0; n < 4; ++n)
                #pragma unroll
                for (int j = 0; j < 4; ++j)
                    lg[h * 16 + rb + j][n * 16 + cb] += acc[h][n][j];
    }
    __syncthreads();

    if (t < BM) {
        float m  = lg[t][0];
        int   mi = 0;
        #pragma unroll
        for (int e = 1; e < NE; ++e) {
            float v = lg[t][e];
            if (v > m) { m = v; mi = e; }
        }
        s_idx[t] = mi;
        out[row0 + t]         = (float)mi;
        out[BATCH + row0 + t] = m;
    }
    __syncthreads();

    // one-hot mask: 32 rows x 64 = 2048 floats; 8/thread, coalesced f32x4
    float* mask = out + 2 * (size_t)BATCH;
    int r  = t >> 3;
    int c0 = (t & 7) * 8;
    int mi = s_idx[r];
    #pragma unroll
    for (int i = 0; i < 2; ++i) {
        f32x4 v;
        #pragma unroll
        for (int j = 0; j < 4; ++j) v[j] = (c0 + i * 4 + j == mi) ? 1.0f : 0.0f;
        *(f32x4*)&mask[(size_t)(row0 + r) * NE + c0 + i * 4] = v;
    }
}

extern "C" void kernel_launch(void* const* d_in, const int* in_sizes, int n_in,
                              void* d_out, int out_size, void* d_ws, size_t ws_size,
                              hipStream_t stream) {
    const float* x = (const float*)d_in[0];
    const float* w = (const float*)d_in[1];
    float* out     = (float*)d_out;

    gate_kernel<<<dim3(BATCH / BM), dim3(NT), 0, stream>>>(x, w, out);
}